// Round 11
// baseline (56.016 us; speedup 1.0000x reference)
//
#include <hip/hip_runtime.h>
#include <hip/hip_bf16.h>

typedef _Float16 f16;
typedef _Float16 f16x8 __attribute__((ext_vector_type(8)));
typedef float f32x4 __attribute__((ext_vector_type(4)));

#define BD 512  // D == H == 512

// async global->LDS, 16B per lane. LDS dest is wave-uniform base + lane*16.
__device__ __forceinline__ void llds16(const f16* g, f16* l) {
  __builtin_amdgcn_global_load_lds(
      (const __attribute__((address_space(1))) unsigned int*)g,
      (__attribute__((address_space(3))) unsigned int*)l,
      16, 0, 0);
}

// ---- fused: weight cvt + x cvt + row norms + novelty partials (512 blocks, 16 rows) ----
__global__ __launch_bounds__(256) void conv_nov_w_kernel(
    const float* __restrict__ x, const float* __restrict__ memf,
    const float* __restrict__ projW, const float* __restrict__ opsW,
    f16* __restrict__ wh, f16* __restrict__ xh,
    float* __restrict__ novPart) {
  __shared__ __align__(16) f16 As[16 * BD];   // 16 KB, chunk-swizzled
  __shared__ float xn[16];
  __shared__ float red[4];
  const int t = threadIdx.x, l = t & 63, w = t >> 6;
  const int rbase = blockIdx.x * 16;

  // weights: 1,048,576 f16 total = 512 blocks * 256 thr * 8 each
  {
    const int e = (blockIdx.x * 256 + t) * 8;
    const float* s = (e < 262144) ? (projW + e) : (opsW + (e - 262144));
    float4 v0 = ((const float4*)s)[0];
    float4 v1 = ((const float4*)s)[1];
    f16x8 h;
    h[0]=(f16)v0.x; h[1]=(f16)v0.y; h[2]=(f16)v0.z; h[3]=(f16)v0.w;
    h[4]=(f16)v1.x; h[5]=(f16)v1.y; h[6]=(f16)v1.z; h[7]=(f16)v1.w;
    *(f16x8*)&wh[e] = h;
  }

  // phase 1: convert rows w*4..w*4+3 (4 waves x 4 rows = 16); lane l covers cols l*8..l*8+7
  #pragma unroll
  for (int rr = 0; rr < 4; ++rr) {
    const int r = w * 4 + rr;
    const float* src = x + (size_t)(rbase + r) * BD + l * 8;
    float4 v0 = *(const float4*)src;
    float4 v1 = *(const float4*)(src + 4);
    f16x8 h;
    h[0]=(f16)v0.x; h[1]=(f16)v0.y; h[2]=(f16)v0.z; h[3]=(f16)v0.w;
    h[4]=(f16)v1.x; h[5]=(f16)v1.y; h[6]=(f16)v1.z; h[7]=(f16)v1.w;
    *(f16x8*)&xh[(size_t)(rbase + r) * BD + l * 8] = h;
    const int cs = l ^ (r & 7);               // chunk swizzle (low 3 bits)
    *(f16x8*)&As[r * BD + cs * 8] = h;
    float ss = v0.x*v0.x + v0.y*v0.y + v0.z*v0.z + v0.w*v0.w
             + v1.x*v1.x + v1.y*v1.y + v1.z*v1.z + v1.w*v1.w;
    #pragma unroll
    for (int off = 32; off; off >>= 1) ss += __shfl_down(ss, off, 64);
    if (l == 0) xn[r] = ss;
  }
  __syncthreads();

  // phase 2: waves 0..3 handle mem rows w*16..+15 (f16 in regs), x rows 0..15
  const int lr = l & 15, lk = l >> 4;
  if (w < 4) {
    const int mm = w * 16 + lr;
    f32x4 acc = (f32x4){0.f, 0.f, 0.f, 0.f};
    float msq = 0.f;
    #pragma unroll
    for (int kk = 0; kk < BD; kk += 32) {
      f16x8 bfr;
      if (mm < 50) {
        const float* ms = memf + (size_t)mm * BD + kk + lk * 8;
        float4 v0 = ((const float4*)ms)[0];
        float4 v1 = ((const float4*)ms)[1];
        bfr[0]=(f16)v0.x; bfr[1]=(f16)v0.y; bfr[2]=(f16)v0.z; bfr[3]=(f16)v0.w;
        bfr[4]=(f16)v1.x; bfr[5]=(f16)v1.y; bfr[6]=(f16)v1.z; bfr[7]=(f16)v1.w;
        msq += v0.x*v0.x + v0.y*v0.y + v0.z*v0.z + v0.w*v0.w
             + v1.x*v1.x + v1.y*v1.y + v1.z*v1.z + v1.w*v1.w;
      } else {
        #pragma unroll
        for (int j = 0; j < 8; ++j) bfr[j] = (f16)0.f;
      }
      const int ch = (kk >> 3) + lk;
      f16x8 a = *(const f16x8*)&As[lr * BD + ((ch ^ (lr & 7)) << 3)];
      acc = __builtin_amdgcn_mfma_f32_16x16x32_f16(a, bfr, acc, 0, 0, 0);
    }
    msq += __shfl_xor(msq, 16, 64);
    msq += __shfl_xor(msq, 32, 64);
    float local = 0.f;
    if (mm < 50) {
      #pragma unroll
      for (int j = 0; j < 4; ++j) {
        const int r0 = lk * 4 + j;             // C/D: row = (lane>>4)*4 + j
        float d = xn[r0] - 2.f * acc[j] + msq;
        local += sqrtf(fmaxf(d, 0.f));
      }
    }
    #pragma unroll
    for (int off = 32; off; off >>= 1) local += __shfl_down(local, off, 64);
    if (l == 0) red[w] = local;
  }
  __syncthreads();
  if (t == 0) novPart[blockIdx.x] = red[0] + red[1] + red[2] + red[3];
}

// ---- GEMM: out = relu(A @ W^T + bias), 64x64 tile, 4 waves of 32x32, BK=64, ring-3 ----
// grid (128,8) = 1024 blocks; 48 KB LDS -> 3 blocks/CU = 12 waves/CU.
// PICK: 0 = proj (also finalizes novelty); 1 = ops_W[idx_a]; 2 = ops_W[idx_b]
template <int PICK, int OUTF16>
__global__ __launch_bounds__(256, 3) void gemm_relu_kernel(
    const f16* __restrict__ A, const f16* __restrict__ Wall,
    const float* __restrict__ ball, const float* __restrict__ logits,
    void* __restrict__ Out, const float* __restrict__ novPart,
    float* __restrict__ novOut) {
  __shared__ __align__(16) char lds[3 * 16384];  // per buf: 8 KB A + 8 KB B

  const int t = threadIdx.x;
  const int l = t & 63;
  const int w = t >> 6;
  const int wr = w >> 1, wc = w & 1;          // wave tile: rows wr*32, cols wc*32
  const int lr = l & 15, lk = l >> 4;

  if (PICK == 0 && blockIdx.x == 0 && blockIdx.y == 0 && w == 0) {
    float s = 0.f;
    #pragma unroll
    for (int i = 0; i < 8; ++i) s += novPart[l + i * 64];
    #pragma unroll
    for (int off = 32; off; off >>= 1) s += __shfl_down(s, off, 64);
    if (l == 0) novOut[0] = fminf(1.5f, s * (1.0f / (8192.0f * 50.0f)));
  }

  int widx = 0;
  if (PICK > 0) {
    float l0 = logits[0], l1 = logits[1], l2 = logits[2];
    int ia = 0; float ba = l0;
    if (l1 > ba) { ba = l1; ia = 1; }
    if (l2 > ba) { ba = l2; ia = 2; }
    if (PICK == 1) {
      widx = ia;
    } else {
      int ib = 0; float bb2 = -3.4e38f;
      if (ia != 0)             { bb2 = l0; ib = 0; }
      if (ia != 1 && l1 > bb2) { bb2 = l1; ib = 1; }
      if (ia != 2 && l2 > bb2) { bb2 = l2; ib = 2; }
      widx = ib;
    }
  }
  const f16* W = Wall + (size_t)widx * BD * BD;
  const float* bias = ball + widx * BD;

  const int rowBase = blockIdx.x * 64;
  const int colBase = blockIdx.y * 64;

  f32x4 acc[2][2];
  #pragma unroll
  for (int m = 0; m < 2; ++m)
    #pragma unroll
    for (int n = 0; n < 2; ++n) acc[m][n] = (f32x4){0.f, 0.f, 0.f, 0.f};

  // stage one K-tile (64x64 A + 64x64 B, 8 KB each): 4 llds16/thread
  auto stage = [&](int buf, int kt) {
    f16* Ab = (f16*)(lds + buf * 16384);
    f16* Bb = (f16*)(lds + buf * 16384 + 8192);
    #pragma unroll
    for (int i = 0; i < 2; ++i) {
      const int o = i * 4096 + t * 16;       // byte offset in 8 KB tile
      const int row = o >> 7;                // 128 B per row (64 f16)
      const int sch = ((o >> 4) & 7) ^ (row & 7);
      llds16(A + (size_t)(rowBase + row) * BD + kt + sch * 8,
             Ab + (i * 4096 + w * 1024) / 2);
      llds16(W + (size_t)(colBase + row) * BD + kt + sch * 8,
             Bb + (i * 4096 + w * 1024) / 2);
    }
  };

  auto compute = [&](int buf) {
    const f16* Ab = (const f16*)(lds + buf * 16384);
    const f16* Bb = (const f16*)(lds + buf * 16384 + 8192);
    #pragma unroll
    for (int kk = 0; kk < 64; kk += 32) {
      const int ch = (kk >> 3) + lk;
      f16x8 af[2], bf[2];
      #pragma unroll
      for (int m = 0; m < 2; ++m) {
        const int row = wr * 32 + m * 16 + lr;
        af[m] = *(const f16x8*)&Ab[row * 64 + ((ch ^ (row & 7)) << 3)];
      }
      #pragma unroll
      for (int n = 0; n < 2; ++n) {
        const int row = wc * 32 + n * 16 + lr;
        bf[n] = *(const f16x8*)&Bb[row * 64 + ((ch ^ (row & 7)) << 3)];
      }
      __builtin_amdgcn_s_setprio(1);
      #pragma unroll
      for (int m = 0; m < 2; ++m)
        #pragma unroll
        for (int n = 0; n < 2; ++n)
          acc[m][n] = __builtin_amdgcn_mfma_f32_16x16x32_f16(af[m], bf[n], acc[m][n], 0, 0, 0);
      __builtin_amdgcn_s_setprio(0);
    }
  };

  // 3-deep ring, ONE barrier per K-step, counted vmcnt (never 0 mid-loop).
  stage(0, 0);
  stage(1, 64);
  #pragma unroll
  for (int t8 = 0; t8 < 8; ++t8) {
    if (t8 < 7) asm volatile("s_waitcnt vmcnt(4)" ::: "memory");
    else        asm volatile("s_waitcnt vmcnt(0)" ::: "memory");
    __builtin_amdgcn_s_barrier();            // tile t8 fully in LDS (all waves)
    if (t8 < 6) stage((t8 + 2) % 3, (t8 + 2) * 64);
    compute(t8 % 3);
    asm volatile("s_waitcnt lgkmcnt(0)" ::: "memory");  // my ds_reads drained
  }

  // epilogue: bias + relu, store
  #pragma unroll
  for (int n = 0; n < 2; ++n) {
    const int col = colBase + wc * 32 + n * 16 + lr;
    const float bbv = bias[col];
    #pragma unroll
    for (int m = 0; m < 2; ++m) {
      #pragma unroll
      for (int j = 0; j < 4; ++j) {
        const int rowg = rowBase + wr * 32 + m * 16 + lk * 4 + j;
        float v = fmaxf(acc[m][n][j] + bbv, 0.f);
        if (OUTF16) ((f16*)Out)[(size_t)rowg * BD + col] = (f16)v;
        else        ((float*)Out)[(size_t)rowg * BD + col] = v;
      }
    }
  }
}

extern "C" void kernel_launch(void* const* d_in, const int* in_sizes, int n_in,
                              void* d_out, int out_size, void* d_ws, size_t ws_size,
                              hipStream_t stream) {
  const float* x      = (const float*)d_in[0];   // [8192,512]
  const float* memf   = (const float*)d_in[1];   // [50,512]
  const float* logits = (const float*)d_in[2];   // [3]
  const float* projW  = (const float*)d_in[3];   // [512,512]
  const float* projB  = (const float*)d_in[4];   // [512]
  const float* opsW   = (const float*)d_in[5];   // [3,512,512]
  const float* opsB   = (const float*)d_in[6];   // [3,512]
  float* out = (float*)d_out;                    // [8192*512 + 1]

  char* ws = (char*)d_ws;
  f16*   xh      = (f16*)(ws);               // 8 MB (x f16; reused as h1)
  f16*   g0      = (f16*)(ws + 8388608);     // 8 MB
  f16*   wh      = (f16*)(ws + 16777216);    // 2 MB: proj_W f16, then ops_W f16
  float* novPart = (float*)(ws + 18874368);  // 2 KB (512 floats)
  f16*   gdup    = (f16*)(ws + 20971520);    // 8 MB dead scratch (measurement)

  conv_nov_w_kernel<<<512, 256, 0, stream>>>(x, memf, projW, opsW, wh, xh, novPart);

  // g0 = relu(xh @ projW^T + projB); also finalizes novelty scalar
  gemm_relu_kernel<0, 1><<<dim3(128, 8), 256, 0, stream>>>(
      xh, wh, projB, logits, (void*)g0, novPart, out + 4194304);
  // MEASUREMENT: identical duplicate of gemm1 into dead scratch. Delta vs r10 = one GEMM's cost.
  gemm_relu_kernel<0, 1><<<dim3(128, 8), 256, 0, stream>>>(
      xh, wh, projB, logits, (void*)gdup, novPart, out + 4194304);
  // h1 = relu(g0 @ Wa^T + ba)   (overwrites xh)
  gemm_relu_kernel<1, 1><<<dim3(128, 8), 256, 0, stream>>>(
      g0, wh + 262144, opsB, logits, (void*)xh, novPart, out + 4194304);
  // out = relu(h1 @ Wb^T + bb)  (fp32 out)
  gemm_relu_kernel<2, 0><<<dim3(128, 8), 256, 0, stream>>>(
      xh, wh + 262144, opsB, logits, (void*)out, novPart, out + 4194304);
}

// Round 12
// 45.657 us; speedup vs baseline: 1.2269x; 1.2269x over previous
//
#include <hip/hip_runtime.h>
#include <hip/hip_bf16.h>

typedef _Float16 f16;
typedef _Float16 f16x4 __attribute__((ext_vector_type(4)));
typedef _Float16 f16x8 __attribute__((ext_vector_type(8)));
typedef float f32x4 __attribute__((ext_vector_type(4)));

#define BD 512  // D == H == 512

// async global->LDS, 16B per lane. LDS dest is wave-uniform base + lane*16.
__device__ __forceinline__ void llds16(const f16* g, f16* l) {
  __builtin_amdgcn_global_load_lds(
      (const __attribute__((address_space(1))) unsigned int*)g,
      (__attribute__((address_space(3))) unsigned int*)l,
      16, 0, 0);
}

// ---- fused: weight cvt + x cvt + LDS-staged mem + novelty (512 blocks, 16 rows) ----
__global__ __launch_bounds__(256, 2) void conv_nov_w_kernel(
    const float* __restrict__ x, const float* __restrict__ memf,
    const float* __restrict__ projW, const float* __restrict__ opsW,
    f16* __restrict__ wh, f16* __restrict__ xh,
    float* __restrict__ novPart) {
  __shared__ __align__(16) f16 memh[52 * BD];  // 52 KB, chunk-swizzled (rows 0..49 valid)
  __shared__ __align__(16) f16 As[16 * BD];    // 16 KB, chunk-swizzled
  __shared__ float xn[16];
  __shared__ float red[4];
  const int t = threadIdx.x, l = t & 63, w = t >> 6;
  const int rbase = blockIdx.x * 16;

  // mem -> LDS f16 (coalesced, swizzled): 50x512 f32 = 6400 float4 = 25/thread
  #pragma unroll
  for (int i = 0; i < 25; ++i) {
    const int idx = i * 256 + t;          // float4 index
    const int row = idx >> 7;             // 128 float4 per row
    const int c4  = idx & 127;
    float4 v = ((const float4*)memf)[(size_t)row * 128 + c4];
    f16x4 h;
    h[0]=(f16)v.x; h[1]=(f16)v.y; h[2]=(f16)v.z; h[3]=(f16)v.w;
    const int ch = c4 >> 1;               // 8-f16 chunk 0..63
    *(f16x4*)&memh[row * BD + (((ch ^ (row & 7)) << 3) | ((c4 & 1) << 2))] = h;
  }

  // weights: 1,048,576 f16 total = 512 blocks * 256 thr * 8 each
  {
    const int e = (blockIdx.x * 256 + t) * 8;
    const float* s = (e < 262144) ? (projW + e) : (opsW + (e - 262144));
    float4 v0 = ((const float4*)s)[0];
    float4 v1 = ((const float4*)s)[1];
    f16x8 h;
    h[0]=(f16)v0.x; h[1]=(f16)v0.y; h[2]=(f16)v0.z; h[3]=(f16)v0.w;
    h[4]=(f16)v1.x; h[5]=(f16)v1.y; h[6]=(f16)v1.z; h[7]=(f16)v1.w;
    *(f16x8*)&wh[e] = h;
  }

  // x cvt: rows w*4..w*4+3; lane l covers cols l*8..l*8+7
  #pragma unroll
  for (int rr = 0; rr < 4; ++rr) {
    const int r = w * 4 + rr;
    const float* src = x + (size_t)(rbase + r) * BD + l * 8;
    float4 v0 = *(const float4*)src;
    float4 v1 = *(const float4*)(src + 4);
    f16x8 h;
    h[0]=(f16)v0.x; h[1]=(f16)v0.y; h[2]=(f16)v0.z; h[3]=(f16)v0.w;
    h[4]=(f16)v1.x; h[5]=(f16)v1.y; h[6]=(f16)v1.z; h[7]=(f16)v1.w;
    *(f16x8*)&xh[(size_t)(rbase + r) * BD + l * 8] = h;
    const int cs = l ^ (r & 7);               // chunk swizzle (low 3 bits)
    *(f16x8*)&As[r * BD + cs * 8] = h;
    float ss = v0.x*v0.x + v0.y*v0.y + v0.z*v0.z + v0.w*v0.w
             + v1.x*v1.x + v1.y*v1.y + v1.z*v1.z + v1.w*v1.w;
    #pragma unroll
    for (int off = 32; off; off >>= 1) ss += __shfl_down(ss, off, 64);
    if (l == 0) xn[r] = ss;
  }
  __syncthreads();

  // novelty: waves 0..3 handle mem rows w*16..+15; all operands from LDS
  const int lr = l & 15, lk = l >> 4;
  if (w < 4) {
    const int mm = w * 16 + lr;
    const bool valid = (mm < 50);
    f32x4 acc = (f32x4){0.f, 0.f, 0.f, 0.f};
    float msq = 0.f;
    #pragma unroll
    for (int kk = 0; kk < BD; kk += 32) {
      const int ch = (kk >> 3) + lk;
      f16x8 bfr;
      if (valid) {
        bfr = *(const f16x8*)&memh[mm * BD + ((ch ^ (mm & 7)) << 3)];
        #pragma unroll
        for (int j = 0; j < 8; ++j) { float f = (float)bfr[j]; msq += f * f; }
      } else {
        #pragma unroll
        for (int j = 0; j < 8; ++j) bfr[j] = (f16)0.f;
      }
      f16x8 a = *(const f16x8*)&As[lr * BD + ((ch ^ (lr & 7)) << 3)];
      acc = __builtin_amdgcn_mfma_f32_16x16x32_f16(a, bfr, acc, 0, 0, 0);
    }
    msq += __shfl_xor(msq, 16, 64);
    msq += __shfl_xor(msq, 32, 64);
    float local = 0.f;
    if (valid) {
      #pragma unroll
      for (int j = 0; j < 4; ++j) {
        const int r0 = lk * 4 + j;             // C/D: row = (lane>>4)*4 + j
        float d = xn[r0] - 2.f * acc[j] + msq;
        local += sqrtf(fmaxf(d, 0.f));
      }
    }
    #pragma unroll
    for (int off = 32; off; off >>= 1) local += __shfl_down(local, off, 64);
    if (l == 0) red[w] = local;
  }
  __syncthreads();
  if (t == 0) novPart[blockIdx.x] = red[0] + red[1] + red[2] + red[3];
}

// ---- GEMM: out = relu(A @ W^T + bias), 64x64 tile, 4 waves of 32x32, BK=64, ring-4 ----
// Deep prefetch: tile t staged 3 steps before use (covers L3 latency on A).
// grid (128,8) = 1024 blocks; 64 KB LDS -> 2 blocks/CU.
// PICK: 0 = proj (also finalizes novelty); 1 = ops_W[idx_a]; 2 = ops_W[idx_b]
template <int PICK, int OUTF16>
__global__ __launch_bounds__(256, 2) void gemm_relu_kernel(
    const f16* __restrict__ A, const f16* __restrict__ Wall,
    const float* __restrict__ ball, const float* __restrict__ logits,
    void* __restrict__ Out, const float* __restrict__ novPart,
    float* __restrict__ novOut) {
  __shared__ __align__(16) char lds[4 * 16384];  // per buf: 8 KB A + 8 KB B

  const int t = threadIdx.x;
  const int l = t & 63;
  const int w = t >> 6;
  const int wr = w >> 1, wc = w & 1;          // wave tile: rows wr*32, cols wc*32
  const int lr = l & 15, lk = l >> 4;

  if (PICK == 0 && blockIdx.x == 0 && blockIdx.y == 0 && w == 0) {
    float s = 0.f;
    #pragma unroll
    for (int i = 0; i < 8; ++i) s += novPart[l + i * 64];
    #pragma unroll
    for (int off = 32; off; off >>= 1) s += __shfl_down(s, off, 64);
    if (l == 0) novOut[0] = fminf(1.5f, s * (1.0f / (8192.0f * 50.0f)));
  }

  int widx = 0;
  if (PICK > 0) {
    float l0 = logits[0], l1 = logits[1], l2 = logits[2];
    int ia = 0; float ba = l0;
    if (l1 > ba) { ba = l1; ia = 1; }
    if (l2 > ba) { ba = l2; ia = 2; }
    if (PICK == 1) {
      widx = ia;
    } else {
      int ib = 0; float bb2 = -3.4e38f;
      if (ia != 0)             { bb2 = l0; ib = 0; }
      if (ia != 1 && l1 > bb2) { bb2 = l1; ib = 1; }
      if (ia != 2 && l2 > bb2) { bb2 = l2; ib = 2; }
      widx = ib;
    }
  }
  const f16* W = Wall + (size_t)widx * BD * BD;
  const float* bias = ball + widx * BD;

  const int rowBase = blockIdx.x * 64;
  const int colBase = blockIdx.y * 64;

  f32x4 acc[2][2];
  #pragma unroll
  for (int m = 0; m < 2; ++m)
    #pragma unroll
    for (int n = 0; n < 2; ++n) acc[m][n] = (f32x4){0.f, 0.f, 0.f, 0.f};

  // stage one K-tile (64x64 A + 64x64 B, 8 KB each): 4 llds16/thread
  auto stage = [&](int buf, int kt) {
    f16* Ab = (f16*)(lds + buf * 16384);
    f16* Bb = (f16*)(lds + buf * 16384 + 8192);
    #pragma unroll
    for (int i = 0; i < 2; ++i) {
      const int o = i * 4096 + t * 16;       // byte offset in 8 KB tile
      const int row = o >> 7;                // 128 B per row (64 f16)
      const int sch = ((o >> 4) & 7) ^ (row & 7);
      llds16(A + (size_t)(rowBase + row) * BD + kt + sch * 8,
             Ab + (i * 4096 + w * 1024) / 2);
      llds16(W + (size_t)(colBase + row) * BD + kt + sch * 8,
             Bb + (i * 4096 + w * 1024) / 2);
    }
  };

  auto compute = [&](int buf) {
    const f16* Ab = (const f16*)(lds + buf * 16384);
    const f16* Bb = (const f16*)(lds + buf * 16384 + 8192);
    #pragma unroll
    for (int kk = 0; kk < 64; kk += 32) {
      const int ch = (kk >> 3) + lk;
      f16x8 af[2], bf[2];
      #pragma unroll
      for (int m = 0; m < 2; ++m) {
        const int row = wr * 32 + m * 16 + lr;
        af[m] = *(const f16x8*)&Ab[row * 64 + ((ch ^ (row & 7)) << 3)];
      }
      #pragma unroll
      for (int n = 0; n < 2; ++n) {
        const int row = wc * 32 + n * 16 + lr;
        bf[n] = *(const f16x8*)&Bb[row * 64 + ((ch ^ (row & 7)) << 3)];
      }
      __builtin_amdgcn_s_setprio(1);
      #pragma unroll
      for (int m = 0; m < 2; ++m)
        #pragma unroll
        for (int n = 0; n < 2; ++n)
          acc[m][n] = __builtin_amdgcn_mfma_f32_16x16x32_f16(af[m], bf[n], acc[m][n], 0, 0, 0);
      __builtin_amdgcn_s_setprio(0);
    }
  };

  // 4-deep ring: tile t lives in buf t&3, staged at step t-3.
  // Per step: wait tile t (vmcnt(8): t+1,t+2 in flight) -> barrier -> stage(t+3)
  // -> compute(t) -> lgkmcnt(0). Never drains the pipe mid-loop.
  stage(0, 0);
  stage(1, 64);
  stage(2, 128);
  #pragma unroll
  for (int t8 = 0; t8 < 8; ++t8) {
    if (t8 < 6)       asm volatile("s_waitcnt vmcnt(8)" ::: "memory");
    else if (t8 == 6) asm volatile("s_waitcnt vmcnt(4)" ::: "memory");
    else              asm volatile("s_waitcnt vmcnt(0)" ::: "memory");
    __builtin_amdgcn_s_barrier();            // tile t8 fully in LDS (all waves)
    if (t8 < 5) stage((t8 + 3) & 3, (t8 + 3) * 64);
    compute(t8 & 3);
    asm volatile("s_waitcnt lgkmcnt(0)" ::: "memory");  // my ds_reads drained
  }

  // epilogue: bias + relu, store
  #pragma unroll
  for (int n = 0; n < 2; ++n) {
    const int col = colBase + wc * 32 + n * 16 + lr;
    const float bbv = bias[col];
    #pragma unroll
    for (int m = 0; m < 2; ++m) {
      #pragma unroll
      for (int j = 0; j < 4; ++j) {
        const int rowg = rowBase + wr * 32 + m * 16 + lk * 4 + j;
        float v = fmaxf(acc[m][n][j] + bbv, 0.f);
        if (OUTF16) ((f16*)Out)[(size_t)rowg * BD + col] = (f16)v;
        else        ((float*)Out)[(size_t)rowg * BD + col] = v;
      }
    }
  }
}

extern "C" void kernel_launch(void* const* d_in, const int* in_sizes, int n_in,
                              void* d_out, int out_size, void* d_ws, size_t ws_size,
                              hipStream_t stream) {
  const float* x      = (const float*)d_in[0];   // [8192,512]
  const float* memf   = (const float*)d_in[1];   // [50,512]
  const float* logits = (const float*)d_in[2];   // [3]
  const float* projW  = (const float*)d_in[3];   // [512,512]
  const float* projB  = (const float*)d_in[4];   // [512]
  const float* opsW   = (const float*)d_in[5];   // [3,512,512]
  const float* opsB   = (const float*)d_in[6];   // [3,512]
  float* out = (float*)d_out;                    // [8192*512 + 1]

  char* ws = (char*)d_ws;
  f16*   xh      = (f16*)(ws);               // 8 MB (x f16; reused as h1)
  f16*   g0      = (f16*)(ws + 8388608);     // 8 MB
  f16*   wh      = (f16*)(ws + 16777216);    // 2 MB: proj_W f16, then ops_W f16
  float* novPart = (float*)(ws + 18874368);  // 2 KB (512 floats)

  conv_nov_w_kernel<<<512, 256, 0, stream>>>(x, memf, projW, opsW, wh, xh, novPart);

  // g0 = relu(xh @ projW^T + projB); also finalizes novelty scalar
  gemm_relu_kernel<0, 1><<<dim3(128, 8), 256, 0, stream>>>(
      xh, wh, projB, logits, (void*)g0, novPart, out + 4194304);
  // h1 = relu(g0 @ Wa^T + ba)   (overwrites xh)
  gemm_relu_kernel<1, 1><<<dim3(128, 8), 256, 0, stream>>>(
      g0, wh + 262144, opsB, logits, (void*)xh, novPart, out + 4194304);
  // out = relu(h1 @ Wb^T + bb)  (fp32 out)
  gemm_relu_kernel<2, 0><<<dim3(128, 8), 256, 0, stream>>>(
      xh, wh + 262144, opsB, logits, (void*)out, novPart, out + 4194304);
}